// Round 6
// baseline (272.061 us; speedup 1.0000x reference)
//
#include <hip/hip_runtime.h>

#define NBATCH 16384
#define NAG 32
#define DOBS 64
#define DH 64
#define DA 16
#define LSTRIDE 72           // shorts per staged h row (144 B: 16B-aligned, spreads banks)
#define HSLOT (16 * LSTRIDE) // shorts per wave h-slot: 16 rows (wave-private)
#define NLDSF 40             // frags 8..47 in LDS; 0..7 (enc_w) + 48..49 (out_w2) via L2
#define NWAVES 4             // 256-thr blocks: 4 waves = 2 pairs; 1-wave/SIMD granularity

// Residency model (R0-R5, gfx950 unified file):
//   true alloc/wave = VGPR_Count(arch) + AccVGPR. Thin 16-row body: 112 + ~32 = ~144.
//   R5 proof: 144 > 128 -> second 512-block reg-blocked (occ 20.5%); 512-thr blocks
//   quantize waves/SIMD in steps of 2, so 3/SIMD is unreachable with them.
// This round: thin body + 256-thr blocks -> 3 blocks/CU = 3 waves/SIMD (needs
//   alloc <= 170 ok, LDS <= 54613: 40960 + 9216 + 2048 = 52224 ok).
//   launch_bounds(256,3) caps combined alloc at ~170; thin body fits, no spill
//   (R4's spill was the fat 32-row body: 164 arch + 64 acc under the same cap).

typedef __attribute__((ext_vector_type(8))) short bf16x8;
typedef __attribute__((ext_vector_type(4))) float f32x4;

__device__ __forceinline__ short f2bf(float f) {        // truncate (activations)
  return (short)(__float_as_uint(f) >> 16);
}
__device__ __forceinline__ short f2bf_rne(float f) {    // RNE (weights, done once)
  unsigned u = __float_as_uint(f);
  return (short)((u + 0x7fffu + ((u >> 16) & 1u)) >> 16);
}

// ---------------------------------------------------------------------------
// Setup: pack all weights into per-lane MFMA B-fragment layout in d_ws (bf16).
//   f 0..7   : enc_w            f 8..23 : W_eff[r]=Wtop-Wbot/31
//   f 24..39 : V[r]=Wbot/31     f 40..47: out_w1      f 48..49: out_w2
// ---------------------------------------------------------------------------
__global__ void build_frags(const float* __restrict__ enc_w, const float* __restrict__ comm_w,
                            const float* __restrict__ out_w1, const float* __restrict__ out_w2,
                            short* __restrict__ wf) {
  int e = blockIdx.x * blockDim.x + threadIdx.x;
  if (e >= 50 * 512) return;
  int f = e >> 9;
  int lane = (e >> 3) & 63;
  int j = e & 7;
  int quad = lane >> 4, col = lane & 15;
  float val;
  if (f < 8) {
    int kk = (f >> 2) & 1, nn = f & 3;
    int k = kk * 32 + quad * 8 + j, n = nn * 16 + col;
    val = enc_w[k * DH + n];
  } else if (f < 24) {
    int g = f - 8; int r = g >> 3, kk = (g >> 2) & 1, nn = g & 3;
    int k = kk * 32 + quad * 8 + j, n = nn * 16 + col;
    const float* W = comm_w + r * (2 * DH * DH);
    val = W[k * DH + n] - W[(DH + k) * DH + n] * (1.0f / 31.0f);
  } else if (f < 40) {
    int g = f - 24; int r = g >> 3, kk = (g >> 2) & 1, nn = g & 3;
    int k = kk * 32 + quad * 8 + j, n = nn * 16 + col;
    const float* W = comm_w + r * (2 * DH * DH);
    val = W[(DH + k) * DH + n] * (1.0f / 31.0f);
  } else if (f < 48) {
    int g = f - 40; int kk = (g >> 2) & 1, nn = g & 3;
    int k = kk * 32 + quad * 8 + j, n = nn * 16 + col;
    val = out_w1[k * DH + n];
  } else {
    int kk = f - 48;
    int k = kk * 32 + quad * 8 + j;
    val = out_w2[k * DA + col];
  }
  wf[e] = f2bf_rne(val);
}

// ---------------------------------------------------------------------------
// 16-row stage: write own h rows (wave-private slot); optional f32 S-partial.
template<bool WITH_T, bool WITH_S>
__device__ __forceinline__ void stage_h(const f32x4 (&acc)[4], const float (&t)[4],
                                        short* hb, float* sp, int quad, int col) {
#pragma unroll
  for (int nn = 0; nn < 4; nn++) {
    float s = 0.f;
#pragma unroll
    for (int r = 0; r < 4; r++) {
      float v = acc[nn][r];
      if constexpr (WITH_T) v += t[nn];
      v = fmaxf(v, 0.f);
      hb[(quad * 4 + r) * LSTRIDE + nn * 16 + col] = f2bf(v);
      if constexpr (WITH_S) s += v;
    }
    if constexpr (WITH_S) {
      s += __shfl_xor(s, 16, 64);     // quad 0^1, 2^3
      s += __shfl_xor(s, 32, 64);     // all quads: sum of this wave's 16 rows
      sp[nn * 16 + col] = s;          // f32 partial (4-way dup write, benign)
    }
  }
}

__device__ __forceinline__ void read_afrags(bf16x8 (&ah)[2], const short* hb, int quad, int col) {
#pragma unroll
  for (int kk = 0; kk < 2; kk++)      // A-frag row = col (0..15): own half only
    ah[kk] = *(const bf16x8*)(hb + col * LSTRIDE + kk * 32 + quad * 8);
}

// combine both halves' f32 partials -> bf16 S frag (row 0 of the extra M-tile)
__device__ __forceinline__ void read_sfrags(bf16x8 (&as)[2], const float* spA, const float* spB,
                                            int quad, int col) {
  const bf16x8 z = {0, 0, 0, 0, 0, 0, 0, 0};
#pragma unroll
  for (int kk = 0; kk < 2; kk++) {
    const float* pa = spA + kk * 32 + quad * 8;
    const float* pb = spB + kk * 32 + quad * 8;
    f32x4 a0 = *(const f32x4*)pa, a1 = *(const f32x4*)(pa + 4);
    f32x4 b0 = *(const f32x4*)pb, b1 = *(const f32x4*)(pb + 4);
    bf16x8 v;
    v[0] = f2bf(a0[0] + b0[0]); v[1] = f2bf(a0[1] + b0[1]);
    v[2] = f2bf(a0[2] + b0[2]); v[3] = f2bf(a0[3] + b0[3]);
    v[4] = f2bf(a1[0] + b1[0]); v[5] = f2bf(a1[1] + b1[1]);
    v[6] = f2bf(a1[2] + b1[2]); v[7] = f2bf(a1[3] + b1[3]);
    as[kk] = (col == 0) ? v : z;
  }
}

// issue global loads for this wave's 16 obs rows (4 x 16B per lane, coalesced)
__device__ __forceinline__ void issue_obs(const float* __restrict__ obs, int b, int hr,
                                          int quad, int col, f32x4 (&pf)[4]) {
#pragma unroll
  for (int kk = 0; kk < 2; kk++) {
    const float* p = obs + ((b * NAG + hr + col) * DOBS + kk * 32 + quad * 8);
    pf[kk * 2 + 0] = *(const f32x4*)p;
    pf[kk * 2 + 1] = *(const f32x4*)(p + 4);
  }
}

__device__ __forceinline__ void issue_avail(const int* __restrict__ avail, int b, int hr,
                                            int quad, int col, int (&pav)[4]) {
#pragma unroll
  for (int r = 0; r < 4; r++)
    pav[r] = avail[(b * NAG + hr + quad * 4 + r) * DA + col];
}

// weight frag f: 0..7 (enc_w) and 48..49 (out_w2) from L2; 8..47 from LDS.
// f is a compile-time constant after unrolling -> no branches.
__device__ __forceinline__ bf16x8 wfrag(const bf16x8* __restrict__ wf,
                                        const short* lw, int f, int lane) {
  return (f < 8 || f >= 48) ? wf[f * 64 + lane]
                            : *(const bf16x8*)(lw + (f - 8) * 512 + lane * 8);
}

// (256,3): combined (VGPR+AGPR) cap ~170/wave; thin body ~144 fits -> no spill,
// and 3 blocks/CU = 3 waves/SIMD become register-feasible.
__global__ void __launch_bounds__(256, 3) commnet_main(
    const float* __restrict__ obs,
    const float* __restrict__ enc_b,
    const float* __restrict__ comm_b,
    const float* __restrict__ out_b1,
    const float* __restrict__ out_b2,
    const int* __restrict__ avail,
    const short* __restrict__ wf_raw,
    float* __restrict__ out) {
  __shared__ short lds_w[NLDSF * 512];    // 40960 B
  __shared__ short hbuf[NWAVES * HSLOT];  //  9216 B (4 wave-private 16-row slots)
  __shared__ float sbuf[2][2][2][64];     //  2048 B (stage, pair, half, col); total 52224
  const int tid = threadIdx.x;
  const int wave = tid >> 6;
  const int lane = tid & 63;
  const int quad = lane >> 4, col = lane & 15;
  const int pair = wave >> 1, half = wave & 1;
  const int hr = half * 16;               // this wave's row base within the batch
  short* hb = hbuf + wave * HSLOT;
  const bf16x8* wf = (const bf16x8*)wf_raw;

  // ---- one-time cooperative weight staging: L2 -> LDS (frags 8..47)
  for (int f = 8 + wave; f < 48; f += NWAVES)
    *(bf16x8*)(lds_w + (f - 8) * 512 + lane * 8) = wf[f * 64 + lane];

  int b = blockIdx.x * 2 + pair;          // 768 blocks * 2 pairs = 1536 batches/sweep
  const int wstep = 1536;                 // 10-11 iterations per pair

  // prefetch first batch (obs + avail) while staging completes
  f32x4 pf[4];
  int pav[4];
  issue_obs(obs, b, hr, quad, col, pf);
  issue_avail(avail, b, hr, quad, col, pav);

  // biases (L2-hot broadcast loads), kept in registers (reg budget has ~26 headroom)
  float eb[4], cbb[2][4], ob1[4];
#pragma unroll
  for (int nn = 0; nn < 4; nn++) {
    eb[nn] = enc_b[nn * 16 + col];
    cbb[0][nn] = comm_b[nn * 16 + col];
    cbb[1][nn] = comm_b[DH + nn * 16 + col];
    ob1[nn] = out_b1[nn * 16 + col];
  }
  float ob2 = out_b2[col];

  __syncthreads();   // all waves see the fully-staged lds_w

#pragma unroll 1
  for (;;) {
    const int bnx = b + wstep;
    const int bn = (bnx < NBATCH) ? bnx : 0;   // last iter: dummy prefetch (L2-hot)

    // ---- convert prefetched obs f32 -> bf16 A-frags, then re-issue pf for bn ----
    bf16x8 aob[2];
#pragma unroll
    for (int kk = 0; kk < 2; kk++) {
      f32x4 x0 = pf[kk * 2 + 0];
      f32x4 x1 = pf[kk * 2 + 1];
      bf16x8 a;
      a[0] = f2bf(x0[0]); a[1] = f2bf(x0[1]); a[2] = f2bf(x0[2]); a[3] = f2bf(x0[3]);
      a[4] = f2bf(x1[0]); a[5] = f2bf(x1[1]); a[6] = f2bf(x1[2]); a[7] = f2bf(x1[3]);
      aob[kk] = a;
    }
    issue_obs(obs, bn, hr, quad, col, pf);   // in flight across the whole batch body

    // ---------------- GEMM1: h0 = relu(obs @ enc_w + enc_b) ----------------
    f32x4 acc[4];
#pragma unroll
    for (int nn = 0; nn < 4; nn++) {
      f32x4 c; c[0] = c[1] = c[2] = c[3] = eb[nn];
      acc[nn] = c;
    }
#pragma unroll
    for (int kk = 0; kk < 2; kk++)
#pragma unroll
      for (int nn = 0; nn < 4; nn++) {
        bf16x8 w = wfrag(wf, lds_w, kk * 4 + nn, lane);
        acc[nn] = __builtin_amdgcn_mfma_f32_16x16x32_bf16(aob[kk], w, acc[nn], 0, 0, 0);
      }
    float tz[4] = {0.f, 0.f, 0.f, 0.f};
    stage_h<false, true>(acc, tz, hb, &sbuf[0][pair][half][0], quad, col);
    __syncthreads();                               // pair's S partials visible
    bf16x8 ah[2]; read_afrags(ah, hb, quad, col);
    bf16x8 as[2]; read_sfrags(as, &sbuf[0][pair][0][0], &sbuf[0][pair][1][0], quad, col);

    // ------------- comm rounds: h = relu(h@W_eff + S@V + b) ---------------
#pragma unroll
    for (int r = 0; r < 2; r++) {
      f32x4 aS[4];
#pragma unroll
      for (int nn = 0; nn < 4; nn++) { f32x4 z; z[0] = z[1] = z[2] = z[3] = 0.f; aS[nn] = z; }
#pragma unroll
      for (int kk = 0; kk < 2; kk++)
#pragma unroll
        for (int nn = 0; nn < 4; nn++) {
          bf16x8 vv = wfrag(wf, lds_w, 24 + r * 8 + kk * 4 + nn, lane);
          aS[nn] = __builtin_amdgcn_mfma_f32_16x16x32_bf16(as[kk], vv, aS[nn], 0, 0, 0);
        }
      float t[4];
#pragma unroll
      for (int nn = 0; nn < 4; nn++) t[nn] = __shfl(aS[nn][0], col, 64);  // row 0 of S-tile

      f32x4 a2[4];
#pragma unroll
      for (int nn = 0; nn < 4; nn++) {
        f32x4 c; c[0] = c[1] = c[2] = c[3] = cbb[r][nn];
        a2[nn] = c;
      }
#pragma unroll
      for (int kk = 0; kk < 2; kk++)
#pragma unroll
        for (int nn = 0; nn < 4; nn++) {
          bf16x8 we = wfrag(wf, lds_w, 8 + r * 8 + kk * 4 + nn, lane);
          a2[nn] = __builtin_amdgcn_mfma_f32_16x16x32_bf16(ah[kk], we, a2[nn], 0, 0, 0);
        }
      if (r == 0) {
        stage_h<true, true>(a2, t, hb, &sbuf[1][pair][half][0], quad, col);
        __syncthreads();                           // barrier #2 (also fences sbuf[0] reuse)
        read_afrags(ah, hb, quad, col);
        read_sfrags(as, &sbuf[1][pair][0][0], &sbuf[1][pair][1][0], quad, col);
      } else {
        stage_h<true, false>(a2, t, hb, nullptr, quad, col);  // h wave-private: no barrier
        read_afrags(ah, hb, quad, col);
      }
    }

    // ---------------- out1: hid = relu(h @ out_w1 + out_b1) ---------------
    f32x4 a3[4];
#pragma unroll
    for (int nn = 0; nn < 4; nn++) {
      f32x4 c; c[0] = c[1] = c[2] = c[3] = ob1[nn];
      a3[nn] = c;
    }
#pragma unroll
    for (int kk = 0; kk < 2; kk++)
#pragma unroll
      for (int nn = 0; nn < 4; nn++) {
        bf16x8 w = wfrag(wf, lds_w, 40 + kk * 4 + nn, lane);
        a3[nn] = __builtin_amdgcn_mfma_f32_16x16x32_bf16(ah[kk], w, a3[nn], 0, 0, 0);
      }
    stage_h<false, false>(a3, tz, hb, nullptr, quad, col);
    read_afrags(ah, hb, quad, col);

    // ---------------- out2 + mask + store ---------------------------------
    f32x4 a4;
    a4[0] = a4[1] = a4[2] = a4[3] = ob2;
#pragma unroll
    for (int kk = 0; kk < 2; kk++) {
      bf16x8 w = wfrag(wf, lds_w, 48 + kk, lane);   // L2 path
      a4 = __builtin_amdgcn_mfma_f32_16x16x32_bf16(ah[kk], w, a4, 0, 0, 0);
    }
#pragma unroll
    for (int r = 0; r < 4; r++) {
      int row = hr + quad * 4 + r;
      int idx = (b * NAG + row) * DA + col;
      out[idx] = (pav[r] == 0) ? -1e10f : a4[r];
    }
    // avail prefetch for next batch AFTER the stores (WAR clear on pav)
    issue_avail(avail, bn, hr, quad, col, pav);

    if (bnx >= NBATCH) break;
    b = bnx;
  }
}

extern "C" void kernel_launch(void* const* d_in, const int* in_sizes, int n_in,
                              void* d_out, int out_size, void* d_ws, size_t ws_size,
                              hipStream_t stream) {
  const float* obs    = (const float*)d_in[0];
  const float* enc_w  = (const float*)d_in[1];
  const float* enc_b  = (const float*)d_in[2];
  const float* comm_w = (const float*)d_in[3];
  const float* comm_b = (const float*)d_in[4];
  const float* out_w1 = (const float*)d_in[5];
  const float* out_b1 = (const float*)d_in[6];
  const float* out_w2 = (const float*)d_in[7];
  const float* out_b2 = (const float*)d_in[8];
  const int*   avail  = (const int*)d_in[9];
  short* wf = (short*)d_ws;  // 50 frags * 512 bf16 = 51200 B of scratch

  build_frags<<<100, 256, 0, stream>>>(enc_w, comm_w, out_w1, out_w2, wf);
  commnet_main<<<768, 256, 0, stream>>>(obs, enc_b, comm_b, out_b1, out_b2, avail, wf,
                                        (float*)d_out);
}

// Round 7
// 250.352 us; speedup vs baseline: 1.0867x; 1.0867x over previous
//
#include <hip/hip_runtime.h>

#define NBATCH 16384
#define NAG 32
#define DOBS 64
#define DH 64
#define DA 16
#define LSTRIDE 72           // shorts per staged h row (144 B: 16B-aligned, spreads banks)
#define HSLOT (16 * LSTRIDE) // shorts per wave h-slot: 16 rows (wave-private)
#define NLDSF 40             // frags 8..47 in LDS; 0..7 (enc_w) + 48..49 (out_w2) via L2
#define NWAVES 4             // 256-thr blocks: 4 waves = 2 pairs; 1-wave/SIMD granularity

// Residency model v3 (R0-R6, gfx950):
//   launch_bounds(_, w) caps ARCH VGPRs at 512/(2w) — allocator assumes acc
//   mirrors arch.  (512,4)->64 [R1], (512,2)->128 [R2,R5], (256,3)->84 [R4,R6].
//   HW residency uses ACTUAL usage: arch + acc.  Thin body: 112 + ~32 = 144
//   -> floor(512/144) = 3 waves/SIMD, reachable only with 1-wave-granular
//   256-thr blocks.  R6 proved LDS 52224 + 3 blocks/CU resident (occ 32%) but
//   the (256,3) cap (84 < 112) forced a spill.  Fix: (256,2) — cap 128 >= 112
//   (no spill), HW fits 3 blocks/CU from actual usage, not the declaration.

typedef __attribute__((ext_vector_type(8))) short bf16x8;
typedef __attribute__((ext_vector_type(4))) float f32x4;

__device__ __forceinline__ short f2bf(float f) {        // truncate (activations)
  return (short)(__float_as_uint(f) >> 16);
}
__device__ __forceinline__ short f2bf_rne(float f) {    // RNE (weights, done once)
  unsigned u = __float_as_uint(f);
  return (short)((u + 0x7fffu + ((u >> 16) & 1u)) >> 16);
}

// ---------------------------------------------------------------------------
// Setup: pack all weights into per-lane MFMA B-fragment layout in d_ws (bf16).
//   f 0..7   : enc_w            f 8..23 : W_eff[r]=Wtop-Wbot/31
//   f 24..39 : V[r]=Wbot/31     f 40..47: out_w1      f 48..49: out_w2
// ---------------------------------------------------------------------------
__global__ void build_frags(const float* __restrict__ enc_w, const float* __restrict__ comm_w,
                            const float* __restrict__ out_w1, const float* __restrict__ out_w2,
                            short* __restrict__ wf) {
  int e = blockIdx.x * blockDim.x + threadIdx.x;
  if (e >= 50 * 512) return;
  int f = e >> 9;
  int lane = (e >> 3) & 63;
  int j = e & 7;
  int quad = lane >> 4, col = lane & 15;
  float val;
  if (f < 8) {
    int kk = (f >> 2) & 1, nn = f & 3;
    int k = kk * 32 + quad * 8 + j, n = nn * 16 + col;
    val = enc_w[k * DH + n];
  } else if (f < 24) {
    int g = f - 8; int r = g >> 3, kk = (g >> 2) & 1, nn = g & 3;
    int k = kk * 32 + quad * 8 + j, n = nn * 16 + col;
    const float* W = comm_w + r * (2 * DH * DH);
    val = W[k * DH + n] - W[(DH + k) * DH + n] * (1.0f / 31.0f);
  } else if (f < 40) {
    int g = f - 24; int r = g >> 3, kk = (g >> 2) & 1, nn = g & 3;
    int k = kk * 32 + quad * 8 + j, n = nn * 16 + col;
    const float* W = comm_w + r * (2 * DH * DH);
    val = W[(DH + k) * DH + n] * (1.0f / 31.0f);
  } else if (f < 48) {
    int g = f - 40; int kk = (g >> 2) & 1, nn = g & 3;
    int k = kk * 32 + quad * 8 + j, n = nn * 16 + col;
    val = out_w1[k * DH + n];
  } else {
    int kk = f - 48;
    int k = kk * 32 + quad * 8 + j;
    val = out_w2[k * DA + col];
  }
  wf[e] = f2bf_rne(val);
}

// ---------------------------------------------------------------------------
// 16-row stage: write own h rows (wave-private slot); optional f32 S-partial.
template<bool WITH_T, bool WITH_S>
__device__ __forceinline__ void stage_h(const f32x4 (&acc)[4], const float (&t)[4],
                                        short* hb, float* sp, int quad, int col) {
#pragma unroll
  for (int nn = 0; nn < 4; nn++) {
    float s = 0.f;
#pragma unroll
    for (int r = 0; r < 4; r++) {
      float v = acc[nn][r];
      if constexpr (WITH_T) v += t[nn];
      v = fmaxf(v, 0.f);
      hb[(quad * 4 + r) * LSTRIDE + nn * 16 + col] = f2bf(v);
      if constexpr (WITH_S) s += v;
    }
    if constexpr (WITH_S) {
      s += __shfl_xor(s, 16, 64);     // quad 0^1, 2^3
      s += __shfl_xor(s, 32, 64);     // all quads: sum of this wave's 16 rows
      sp[nn * 16 + col] = s;          // f32 partial (4-way dup write, benign)
    }
  }
}

__device__ __forceinline__ void read_afrags(bf16x8 (&ah)[2], const short* hb, int quad, int col) {
#pragma unroll
  for (int kk = 0; kk < 2; kk++)      // A-frag row = col (0..15): own half only
    ah[kk] = *(const bf16x8*)(hb + col * LSTRIDE + kk * 32 + quad * 8);
}

// combine both halves' f32 partials -> bf16 S frag (row 0 of the extra M-tile)
__device__ __forceinline__ void read_sfrags(bf16x8 (&as)[2], const float* spA, const float* spB,
                                            int quad, int col) {
  const bf16x8 z = {0, 0, 0, 0, 0, 0, 0, 0};
#pragma unroll
  for (int kk = 0; kk < 2; kk++) {
    const float* pa = spA + kk * 32 + quad * 8;
    const float* pb = spB + kk * 32 + quad * 8;
    f32x4 a0 = *(const f32x4*)pa, a1 = *(const f32x4*)(pa + 4);
    f32x4 b0 = *(const f32x4*)pb, b1 = *(const f32x4*)(pb + 4);
    bf16x8 v;
    v[0] = f2bf(a0[0] + b0[0]); v[1] = f2bf(a0[1] + b0[1]);
    v[2] = f2bf(a0[2] + b0[2]); v[3] = f2bf(a0[3] + b0[3]);
    v[4] = f2bf(a1[0] + b1[0]); v[5] = f2bf(a1[1] + b1[1]);
    v[6] = f2bf(a1[2] + b1[2]); v[7] = f2bf(a1[3] + b1[3]);
    as[kk] = (col == 0) ? v : z;
  }
}

// issue global loads for this wave's 16 obs rows (4 x 16B per lane, coalesced)
__device__ __forceinline__ void issue_obs(const float* __restrict__ obs, int b, int hr,
                                          int quad, int col, f32x4 (&pf)[4]) {
#pragma unroll
  for (int kk = 0; kk < 2; kk++) {
    const float* p = obs + ((b * NAG + hr + col) * DOBS + kk * 32 + quad * 8);
    pf[kk * 2 + 0] = *(const f32x4*)p;
    pf[kk * 2 + 1] = *(const f32x4*)(p + 4);
  }
}

__device__ __forceinline__ void issue_avail(const int* __restrict__ avail, int b, int hr,
                                            int quad, int col, int (&pav)[4]) {
#pragma unroll
  for (int r = 0; r < 4; r++)
    pav[r] = avail[(b * NAG + hr + quad * 4 + r) * DA + col];
}

// weight frag f: 0..7 (enc_w) and 48..49 (out_w2) from L2; 8..47 from LDS.
// f is a compile-time constant after unrolling -> no branches.
__device__ __forceinline__ bf16x8 wfrag(const bf16x8* __restrict__ wf,
                                        const short* lw, int f, int lane) {
  return (f < 8 || f >= 48) ? wf[f * 64 + lane]
                            : *(const bf16x8*)(lw + (f - 8) * 512 + lane * 8);
}

// (256,2): allocator cap 128 arch >= 112 needed -> NO spill. HW residency from
// actual usage (112 arch + ~32 acc = 144) -> 3 waves/SIMD -> 3 blocks/CU with
// LDS 52224 <= 54613. (256,3)'s cap of 84 was what forced R6's spill.
__global__ void __launch_bounds__(256, 2) commnet_main(
    const float* __restrict__ obs,
    const float* __restrict__ enc_b,
    const float* __restrict__ comm_b,
    const float* __restrict__ out_b1,
    const float* __restrict__ out_b2,
    const int* __restrict__ avail,
    const short* __restrict__ wf_raw,
    float* __restrict__ out) {
  __shared__ short lds_w[NLDSF * 512];    // 40960 B
  __shared__ short hbuf[NWAVES * HSLOT];  //  9216 B (4 wave-private 16-row slots)
  __shared__ float sbuf[2][2][2][64];     //  2048 B (stage, pair, half, col); total 52224
  const int tid = threadIdx.x;
  const int wave = tid >> 6;
  const int lane = tid & 63;
  const int quad = lane >> 4, col = lane & 15;
  const int pair = wave >> 1, half = wave & 1;
  const int hr = half * 16;               // this wave's row base within the batch
  short* hb = hbuf + wave * HSLOT;
  const bf16x8* wf = (const bf16x8*)wf_raw;

  // ---- one-time cooperative weight staging: L2 -> LDS (frags 8..47)
  for (int f = 8 + wave; f < 48; f += NWAVES)
    *(bf16x8*)(lds_w + (f - 8) * 512 + lane * 8) = wf[f * 64 + lane];

  int b = blockIdx.x * 2 + pair;          // 768 blocks * 2 pairs = 1536 batches/sweep
  const int wstep = 1536;                 // 10-11 iterations per pair

  // prefetch first batch (obs + avail) while staging completes
  f32x4 pf[4];
  int pav[4];
  issue_obs(obs, b, hr, quad, col, pf);
  issue_avail(avail, b, hr, quad, col, pav);

  // biases (L2-hot broadcast loads), kept in registers
  float eb[4], cbb[2][4], ob1[4];
#pragma unroll
  for (int nn = 0; nn < 4; nn++) {
    eb[nn] = enc_b[nn * 16 + col];
    cbb[0][nn] = comm_b[nn * 16 + col];
    cbb[1][nn] = comm_b[DH + nn * 16 + col];
    ob1[nn] = out_b1[nn * 16 + col];
  }
  float ob2 = out_b2[col];

  __syncthreads();   // all waves see the fully-staged lds_w

#pragma unroll 1
  for (;;) {
    const int bnx = b + wstep;
    const int bn = (bnx < NBATCH) ? bnx : 0;   // last iter: dummy prefetch (L2-hot)

    // ---- convert prefetched obs f32 -> bf16 A-frags, then re-issue pf for bn ----
    bf16x8 aob[2];
#pragma unroll
    for (int kk = 0; kk < 2; kk++) {
      f32x4 x0 = pf[kk * 2 + 0];
      f32x4 x1 = pf[kk * 2 + 1];
      bf16x8 a;
      a[0] = f2bf(x0[0]); a[1] = f2bf(x0[1]); a[2] = f2bf(x0[2]); a[3] = f2bf(x0[3]);
      a[4] = f2bf(x1[0]); a[5] = f2bf(x1[1]); a[6] = f2bf(x1[2]); a[7] = f2bf(x1[3]);
      aob[kk] = a;
    }
    issue_obs(obs, bn, hr, quad, col, pf);   // in flight across the whole batch body

    // ---------------- GEMM1: h0 = relu(obs @ enc_w + enc_b) ----------------
    f32x4 acc[4];
#pragma unroll
    for (int nn = 0; nn < 4; nn++) {
      f32x4 c; c[0] = c[1] = c[2] = c[3] = eb[nn];
      acc[nn] = c;
    }
#pragma unroll
    for (int kk = 0; kk < 2; kk++)
#pragma unroll
      for (int nn = 0; nn < 4; nn++) {
        bf16x8 w = wfrag(wf, lds_w, kk * 4 + nn, lane);
        acc[nn] = __builtin_amdgcn_mfma_f32_16x16x32_bf16(aob[kk], w, acc[nn], 0, 0, 0);
      }
    float tz[4] = {0.f, 0.f, 0.f, 0.f};
    stage_h<false, true>(acc, tz, hb, &sbuf[0][pair][half][0], quad, col);
    __syncthreads();                               // pair's S partials visible
    bf16x8 ah[2]; read_afrags(ah, hb, quad, col);
    bf16x8 as[2]; read_sfrags(as, &sbuf[0][pair][0][0], &sbuf[0][pair][1][0], quad, col);

    // ------------- comm rounds: h = relu(h@W_eff + S@V + b) ---------------
#pragma unroll
    for (int r = 0; r < 2; r++) {
      f32x4 aS[4];
#pragma unroll
      for (int nn = 0; nn < 4; nn++) { f32x4 z; z[0] = z[1] = z[2] = z[3] = 0.f; aS[nn] = z; }
#pragma unroll
      for (int kk = 0; kk < 2; kk++)
#pragma unroll
        for (int nn = 0; nn < 4; nn++) {
          bf16x8 vv = wfrag(wf, lds_w, 24 + r * 8 + kk * 4 + nn, lane);
          aS[nn] = __builtin_amdgcn_mfma_f32_16x16x32_bf16(as[kk], vv, aS[nn], 0, 0, 0);
        }
      float t[4];
#pragma unroll
      for (int nn = 0; nn < 4; nn++) t[nn] = __shfl(aS[nn][0], col, 64);  // row 0 of S-tile

      f32x4 a2[4];
#pragma unroll
      for (int nn = 0; nn < 4; nn++) {
        f32x4 c; c[0] = c[1] = c[2] = c[3] = cbb[r][nn];
        a2[nn] = c;
      }
#pragma unroll
      for (int kk = 0; kk < 2; kk++)
#pragma unroll
        for (int nn = 0; nn < 4; nn++) {
          bf16x8 we = wfrag(wf, lds_w, 8 + r * 8 + kk * 4 + nn, lane);
          a2[nn] = __builtin_amdgcn_mfma_f32_16x16x32_bf16(ah[kk], we, a2[nn], 0, 0, 0);
        }
      if (r == 0) {
        stage_h<true, true>(a2, t, hb, &sbuf[1][pair][half][0], quad, col);
        __syncthreads();                           // barrier #2 (also fences sbuf[0] reuse)
        read_afrags(ah, hb, quad, col);
        read_sfrags(as, &sbuf[1][pair][0][0], &sbuf[1][pair][1][0], quad, col);
      } else {
        stage_h<true, false>(a2, t, hb, nullptr, quad, col);  // h wave-private: no barrier
        read_afrags(ah, hb, quad, col);
      }
    }

    // ---------------- out1: hid = relu(h @ out_w1 + out_b1) ---------------
    f32x4 a3[4];
#pragma unroll
    for (int nn = 0; nn < 4; nn++) {
      f32x4 c; c[0] = c[1] = c[2] = c[3] = ob1[nn];
      a3[nn] = c;
    }
#pragma unroll
    for (int kk = 0; kk < 2; kk++)
#pragma unroll
      for (int nn = 0; nn < 4; nn++) {
        bf16x8 w = wfrag(wf, lds_w, 40 + kk * 4 + nn, lane);
        a3[nn] = __builtin_amdgcn_mfma_f32_16x16x32_bf16(ah[kk], w, a3[nn], 0, 0, 0);
      }
    stage_h<false, false>(a3, tz, hb, nullptr, quad, col);
    read_afrags(ah, hb, quad, col);

    // ---------------- out2 + mask + store ---------------------------------
    f32x4 a4;
    a4[0] = a4[1] = a4[2] = a4[3] = ob2;
#pragma unroll
    for (int kk = 0; kk < 2; kk++) {
      bf16x8 w = wfrag(wf, lds_w, 48 + kk, lane);   // L2 path
      a4 = __builtin_amdgcn_mfma_f32_16x16x32_bf16(ah[kk], w, a4, 0, 0, 0);
    }
#pragma unroll
    for (int r = 0; r < 4; r++) {
      int row = hr + quad * 4 + r;
      int idx = (b * NAG + row) * DA + col;
      out[idx] = (pav[r] == 0) ? -1e10f : a4[r];
    }
    // avail prefetch for next batch AFTER the stores (WAR clear on pav)
    issue_avail(avail, bn, hr, quad, col, pav);

    if (bnx >= NBATCH) break;
    b = bnx;
  }
}

extern "C" void kernel_launch(void* const* d_in, const int* in_sizes, int n_in,
                              void* d_out, int out_size, void* d_ws, size_t ws_size,
                              hipStream_t stream) {
  const float* obs    = (const float*)d_in[0];
  const float* enc_w  = (const float*)d_in[1];
  const float* enc_b  = (const float*)d_in[2];
  const float* comm_w = (const float*)d_in[3];
  const float* comm_b = (const float*)d_in[4];
  const float* out_w1 = (const float*)d_in[5];
  const float* out_b1 = (const float*)d_in[6];
  const float* out_w2 = (const float*)d_in[7];
  const float* out_b2 = (const float*)d_in[8];
  const int*   avail  = (const int*)d_in[9];
  short* wf = (short*)d_ws;  // 50 frags * 512 bf16 = 51200 B of scratch

  build_frags<<<100, 256, 0, stream>>>(enc_w, comm_w, out_w1, out_w2, wf);
  commnet_main<<<768, 256, 0, stream>>>(obs, enc_b, comm_b, out_b1, out_b2, avail, wf,
                                        (float*)d_out);
}